// Round 2
// baseline (583.246 us; speedup 1.0000x reference)
//
#include <hip/hip_runtime.h>

typedef float f4 __attribute__((ext_vector_type(4)));

#define NAT   64
#define EDIM  128
#define GTOT  110592        // 48^3
#define BG    64            // grid points per inner iteration
#define GPB   1728          // grid points per block (27 * 64)
#define ITERS 27
#define OUTOFF 442368       // 4 * 110592  (output 0 size; c starts after)

__global__ __launch_bounds__(256, 1)
void density_fused_kernel(const float* __restrict__ pos,
                          const float* __restrict__ nf,
                          const float* __restrict__ origin,
                          const float* __restrict__ lattice,
                          const float* __restrict__ scaleP,
                          const float* __restrict__ W1,
                          const float* __restrict__ b1,
                          const float* __restrict__ W2,
                          const float* __restrict__ b2,
                          const int*   __restrict__ batch_nodes,
                          float* __restrict__ outBase,
                          float* __restrict__ cAll)
{
    __shared__ float sNF[NAT][EDIM];    // 32 KB
    __shared__ float sW1[EDIM][EDIM];   // 64 KB
    __shared__ float sWt[NAT][BG];      // 16 KB  (transposed weights wT[n][g])
    __shared__ float sX [BG][EDIM];     // 32 KB
    __shared__ float sPos[NAT*3];
    __shared__ float sW2[EDIM];
    __shared__ float sB1[EDIM];

    const int t     = threadIdx.x;
    const int batch = blockIdx.x >> 6;   // 64 blocks per batch
    const int chunk = blockIdx.x & 63;
    const int gstart = chunk * GPB;

    // ---- one-time staging ----
    const float* nfB = nf + batch * (NAT*EDIM);
    #pragma unroll
    for (int i = 0; i < 8; ++i)          // 2048 f4 / 256 threads
        ((f4*)sNF)[t + i*256] = ((const f4*)nfB)[t + i*256];
    #pragma unroll
    for (int i = 0; i < 16; ++i)         // 4096 f4 / 256 threads
        ((f4*)sW1)[t + i*256] = ((const f4*)W1)[t + i*256];
    if (t < EDIM) { sW2[t] = W2[t]; sB1[t] = b1[t]; }
    if (t < NAT*3) sPos[t] = pos[batch*NAT*3 + t];

    const float scale = scaleP[0];
    const float s2    = scale * scale;
    const int   nb    = batch_nodes[batch];
    const float b2v   = b2[0];
    const float ox = origin[batch*3+0], oy = origin[batch*3+1], oz = origin[batch*3+2];
    const float stx = lattice[batch*9+0] * (1.0f/47.0f);   // linspace(0,1,48) step
    const float sty = lattice[batch*9+4] * (1.0f/47.0f);
    const float stz = lattice[batch*9+8] * (1.0f/47.0f);

    __syncthreads();

    const int eq = t & 31;     // e-column group (32 cover 128 channels, 4 each)
    const int gq = t >> 5;     // grid-point group (8 groups of 8)
    const int e0 = eq * 4;
    const int gb = gq * 8;

    float* cB = cAll   + (size_t)batch * GTOT * EDIM;
    float* oB = outBase + (size_t)batch * GTOT;

    const f4 bv  = *(const f4*)&sB1[e0];
    const f4 w2v = *(const f4*)&sW2[e0];

    for (int it = 0; it < ITERS; ++it) {
        const int g0 = gstart + it * BG;

        // ---- stage 1: Lorentzian weights into sWt[n][g] ----
        {
            const int gl = t & 63;
            const unsigned g  = (unsigned)(g0 + gl);
            const unsigned iz = g % 48u;
            const unsigned r  = g / 48u;
            const unsigned iy = r % 48u;
            const unsigned ix = r / 48u;
            const float gx = ox + (float)ix * stx;
            const float gy = oy + (float)iy * sty;
            const float gz = oz + (float)iz * stz;
            const int nbase = t >> 6;          // 0..3
            #pragma unroll
            for (int nn = 0; nn < 16; ++nn) {
                const int n = nbase + nn * 4;
                const float dx = gx - sPos[n*3+0];
                const float dy = gy - sPos[n*3+1];
                const float dz = gz - sPos[n*3+2];
                const float d2 = dx*dx + dy*dy + dz*dz;
                sWt[n][gl] = (n < nb) ? (scale / (s2 + d2)) : 0.0f;
            }
        }
        __syncthreads();

        // ---- stage 2: x[g][e] = sum_n w[g][n] * NF[n][e] ----
        f4 acc[8];
        const f4 z = {0.f, 0.f, 0.f, 0.f};
        #pragma unroll
        for (int j = 0; j < 8; ++j) acc[j] = z;

        #pragma unroll 4
        for (int n = 0; n < NAT; ++n) {
            const f4 nfv = *(const f4*)&sNF[n][e0];
            const f4 wa  = *(const f4*)&sWt[n][gb];
            const f4 wb  = *(const f4*)&sWt[n][gb+4];
            acc[0] += nfv * wa[0];
            acc[1] += nfv * wa[1];
            acc[2] += nfv * wa[2];
            acc[3] += nfv * wa[3];
            acc[4] += nfv * wb[0];
            acc[5] += nfv * wb[1];
            acc[6] += nfv * wb[2];
            acc[7] += nfv * wb[3];
        }

        // write c (coalesced f4) and sX for the second GEMM
        #pragma unroll
        for (int j = 0; j < 8; ++j) {
            *(f4*)&cB[(size_t)(g0 + gb + j) * EDIM + e0] = acc[j];
            *(f4*)&sX[gb + j][e0] = acc[j];
        }
        __syncthreads();

        // ---- stage 3: h[g][e] = x[g][:] @ W1[:][e] + b1[e] ----
        f4 h[8];
        #pragma unroll
        for (int j = 0; j < 8; ++j) h[j] = bv;

        #pragma unroll 2
        for (int kk = 0; kk < EDIM; kk += 4) {
            const f4 w1r0 = *(const f4*)&sW1[kk+0][e0];
            const f4 w1r1 = *(const f4*)&sW1[kk+1][e0];
            const f4 w1r2 = *(const f4*)&sW1[kk+2][e0];
            const f4 w1r3 = *(const f4*)&sW1[kk+3][e0];
            #pragma unroll
            for (int j = 0; j < 8; ++j) {
                const f4 xv = *(const f4*)&sX[gb + j][kk];   // 32-lane broadcast
                h[j] += w1r0 * xv[0];
                h[j] += w1r1 * xv[1];
                h[j] += w1r2 * xv[2];
                h[j] += w1r3 * xv[3];
            }
        }

        // ---- stage 4: out[g] = relu(h) @ W2 + b2 ----
        #pragma unroll
        for (int j = 0; j < 8; ++j) {
            float p = fmaxf(h[j][0], 0.f) * w2v[0]
                    + fmaxf(h[j][1], 0.f) * w2v[1]
                    + fmaxf(h[j][2], 0.f) * w2v[2]
                    + fmaxf(h[j][3], 0.f) * w2v[3];
            p += __shfl_xor(p, 1, 64);
            p += __shfl_xor(p, 2, 64);
            p += __shfl_xor(p, 4, 64);
            p += __shfl_xor(p, 8, 64);
            p += __shfl_xor(p, 16, 64);
            if (eq == 0) oB[g0 + gb + j] = p + b2v;
        }
        // next-iteration hazards are covered by the two barriers above
    }
}

extern "C" void kernel_launch(void* const* d_in, const int* in_sizes, int n_in,
                              void* d_out, int out_size, void* d_ws, size_t ws_size,
                              hipStream_t stream) {
    const float* pos     = (const float*)d_in[0];
    const float* nodef   = (const float*)d_in[1];
    const float* origin  = (const float*)d_in[2];
    const float* lattice = (const float*)d_in[3];
    const float* scale   = (const float*)d_in[4];
    const float* W1      = (const float*)d_in[5];
    const float* b1      = (const float*)d_in[6];
    const float* W2      = (const float*)d_in[7];
    const float* b2      = (const float*)d_in[8];
    const int*   bn      = (const int*)d_in[9];
    float* outP = (float*)d_out;
    float* cP   = outP + OUTOFF;

    hipLaunchKernelGGL(density_fused_kernel, dim3(256), dim3(256), 0, stream,
                       pos, nodef, origin, lattice, scale, W1, b1, W2, b2, bn,
                       outP, cP);
}

// Round 5
// 290.530 us; speedup vs baseline: 2.0075x; 2.0075x over previous
//
#include <hip/hip_runtime.h>

typedef float f4 __attribute__((ext_vector_type(4)));
typedef float f32x4 __attribute__((ext_vector_type(4)));
typedef short short8 __attribute__((ext_vector_type(8)));   // 8 bf16 = 4 VGPR MFMA operand

#define NAT    64
#define EDIM   128
#define GTOT   110592        // 48^3
#define TILES  8             // 64-row tiles per block
#define CPB    216           // chunks (blocks) per batch: 216*8*64 = 110592
#define OUTOFF 442368        // 4*110592, c follows out in d_out

__device__ __forceinline__ unsigned short f2bf(float f) {
    unsigned u = __builtin_bit_cast(unsigned, f);
    u += 0x7FFFu + ((u >> 16) & 1u);          // RNE (finite values only)
    return (unsigned short)(u >> 16);
}
__device__ __forceinline__ unsigned pack2(float a, float b) {
    return (unsigned)f2bf(a) | ((unsigned)f2bf(b) << 16);
}

__global__ __launch_bounds__(256, 2)
void density_mfma_kernel(const float* __restrict__ pos,
                         const float* __restrict__ nf,
                         const float* __restrict__ origin,
                         const float* __restrict__ lattice,
                         const float* __restrict__ scaleP,
                         const float* __restrict__ W1,
                         const float* __restrict__ b1,
                         const float* __restrict__ W2,
                         const float* __restrict__ b2,
                         const int*   __restrict__ batch_nodes,
                         float* __restrict__ outBase,
                         float* __restrict__ cAll)
{
    // padded bf16 LDS tiles: row strides 144B / 272B (16B-aligned, odd 16B-multiple -> 2-way banks)
    __shared__ __attribute__((aligned(16))) unsigned short sNFt[EDIM][72];   // NF^T [e][n]   18432 B
    __shared__ __attribute__((aligned(16))) unsigned short sW1t[EDIM][136];  // W1^T [eo][k]  34816 B
    __shared__ __attribute__((aligned(16))) unsigned short sW  [64][72];     // w    [g][n]    9216 B
    __shared__ __attribute__((aligned(16))) unsigned short sXb [64][136];    // x    [g][k]   17408 B
    __shared__ float sPos[NAT*3];                                            //                 768 B
    __shared__ float sP[4][64];                                              //                1024 B

    const int t    = threadIdx.x;
    const int lane = t & 63;
    const int wv   = t >> 6;        // wave id 0..3
    const int q    = lane >> 4;     // quarter-wave 0..3
    const int a15  = lane & 15;

    const int batch  = blockIdx.x / CPB;
    const int chunk  = blockIdx.x % CPB;
    const int gstart = chunk * (TILES * 64);

    // ---- one-time staging ----
    const f4* nfB = (const f4*)(nf + (size_t)batch * NAT * EDIM);
    #pragma unroll
    for (int i = 0; i < 8; ++i) {                 // 2048 f4
        const int qi = t + i * 256;
        const int n  = qi >> 5;                   // NF row (atom)
        const int e4 = qi & 31;                   // f4 col block
        const f4 v = nfB[qi];
        #pragma unroll
        for (int j = 0; j < 4; ++j) sNFt[e4*4 + j][n] = f2bf(v[j]);
    }
    #pragma unroll
    for (int i = 0; i < 16; ++i) {                // 4096 f4
        const int qi = t + i * 256;
        const int k  = qi >> 5;                   // W1 row (input channel)
        const int e4 = qi & 31;
        const f4 v = ((const f4*)W1)[qi];
        #pragma unroll
        for (int j = 0; j < 4; ++j) sW1t[e4*4 + j][k] = f2bf(v[j]);
    }
    if (t < NAT*3) sPos[t] = pos[batch*NAT*3 + t];

    const float scale = scaleP[0];
    const float s2    = scale * scale;
    const int   nb    = batch_nodes[batch];
    const float b2v   = b2[0];
    const float ox = origin[batch*3+0], oy = origin[batch*3+1], oz = origin[batch*3+2];
    const float stx = lattice[batch*9+0] * (1.0f/47.0f);
    const float sty = lattice[batch*9+4] * (1.0f/47.0f);
    const float stz = lattice[batch*9+8] * (1.0f/47.0f);

    const int   e0w  = wv * 32;                   // this wave's 32 output cols
    const float b1v0 = b1[e0w + a15],      b1v1 = b1[e0w + 16 + a15];
    const float w2v0 = W2[e0w + a15],      w2v1 = W2[e0w + 16 + a15];

    float* cB = cAll    + (size_t)batch * GTOT * EDIM;
    float* oB = outBase + (size_t)batch * GTOT;

    __syncthreads();   // staging visible

    for (int it = 0; it < TILES; ++it) {
        const int g0 = gstart + it * 64;

        // ---- stage 1: Lorentzian weights -> sW (bf16) ----
        {
            const unsigned g   = (unsigned)(g0 + lane);
            const unsigned ix  = g / 2304u;
            const unsigned rem = g - ix * 2304u;
            const unsigned iy  = rem / 48u;
            const unsigned iz  = rem - iy * 48u;
            const float gx = ox + (float)ix * stx;
            const float gy = oy + (float)iy * sty;
            const float gz = oz + (float)iz * stz;
            #pragma unroll
            for (int i = 0; i < 8; ++i) {         // 16 atoms per wave, as pairs
                const int n0 = wv * 16 + i * 2;
                float wvv[2];
                #pragma unroll
                for (int u = 0; u < 2; ++u) {
                    const int n = n0 + u;
                    const float dx = gx - sPos[n*3+0];
                    const float dy = gy - sPos[n*3+1];
                    const float dz = gz - sPos[n*3+2];
                    const float d2 = dx*dx + dy*dy + dz*dz;
                    const float val = scale * __builtin_amdgcn_rcpf(s2 + d2);
                    wvv[u] = (n < nb) ? val : 0.0f;
                }
                *(unsigned*)&sW[lane][n0] = pack2(wvv[0], wvv[1]);
            }
        }
        __syncthreads();                          // (1) sW ready

        // ---- GEMM1: x[64g x 128e] = w[64 x 64] @ NF[64 x 128], wave owns 32 e-cols ----
        f32x4 acc[4][2];
        #pragma unroll
        for (int gt = 0; gt < 4; ++gt)
            #pragma unroll
            for (int et = 0; et < 2; ++et)
                acc[gt][et] = (f32x4){0.f, 0.f, 0.f, 0.f};

        #pragma unroll
        for (int ks = 0; ks < 2; ++ks) {
            short8 afr[4], bfr[2];
            #pragma unroll
            for (int gt = 0; gt < 4; ++gt)
                afr[gt] = *(const short8*)&sW[gt*16 + a15][ks*32 + q*8];
            #pragma unroll
            for (int et = 0; et < 2; ++et)
                bfr[et] = *(const short8*)&sNFt[e0w + et*16 + a15][ks*32 + q*8];
            #pragma unroll
            for (int gt = 0; gt < 4; ++gt)
                #pragma unroll
                for (int et = 0; et < 2; ++et)
                    acc[gt][et] = __builtin_amdgcn_mfma_f32_16x16x32_bf16(
                        afr[gt], bfr[et], acc[gt][et], 0, 0, 0);
        }

        // c stores (fp32 from acc, dense) + sXb (bf16 for GEMM2 A-fragments)
        #pragma unroll
        for (int gt = 0; gt < 4; ++gt) {
            float* cp = cB + (size_t)(g0 + gt*16 + q*4) * EDIM + e0w + a15;
            #pragma unroll
            for (int et = 0; et < 2; ++et) {
                #pragma unroll
                for (int r = 0; r < 4; ++r) {
                    cp[r*EDIM + et*16] = acc[gt][et][r];
                    sXb[gt*16 + q*4 + r][e0w + et*16 + a15] = f2bf(acc[gt][et][r]);
                }
            }
        }
        __syncthreads();                          // (2) sXb ready

        // ---- GEMM2: h[64 x 128] = x[64 x 128] @ W1[128 x 128], wave owns 32 eo-cols ----
        f32x4 h[4][2];
        #pragma unroll
        for (int gt = 0; gt < 4; ++gt)
            #pragma unroll
            for (int et = 0; et < 2; ++et)
                h[gt][et] = (f32x4){0.f, 0.f, 0.f, 0.f};

        #pragma unroll
        for (int ks = 0; ks < 4; ++ks) {
            short8 xa[4], wb[2];
            #pragma unroll
            for (int gt = 0; gt < 4; ++gt)
                xa[gt] = *(const short8*)&sXb[gt*16 + a15][ks*32 + q*8];
            #pragma unroll
            for (int et = 0; et < 2; ++et)
                wb[et] = *(const short8*)&sW1t[e0w + et*16 + a15][ks*32 + q*8];
            #pragma unroll
            for (int gt = 0; gt < 4; ++gt)
                #pragma unroll
                for (int et = 0; et < 2; ++et)
                    h[gt][et] = __builtin_amdgcn_mfma_f32_16x16x32_bf16(
                        xa[gt], wb[et], h[gt][et], 0, 0, 0);
        }

        // ---- stage 4: out = relu(h + b1) @ W2 + b2 ----
        #pragma unroll
        for (int gt = 0; gt < 4; ++gt) {
            f4 pv;
            #pragma unroll
            for (int r = 0; r < 4; ++r) {
                float p = fmaxf(h[gt][0][r] + b1v0, 0.f) * w2v0
                        + fmaxf(h[gt][1][r] + b1v1, 0.f) * w2v1;
                p += __shfl_xor(p, 1, 64);
                p += __shfl_xor(p, 2, 64);
                p += __shfl_xor(p, 4, 64);
                p += __shfl_xor(p, 8, 64);
                pv[r] = p;
            }
            if (a15 == 0) *(f4*)&sP[wv][gt*16 + q*4] = pv;
        }
        __syncthreads();                          // (3) sP ready

        if (t < 64) {
            const float o = sP[0][t] + sP[1][t] + sP[2][t] + sP[3][t] + b2v;
            oB[g0 + t] = o;
        }
        // next iter: stage1 writes sW (readers done before barrier 2);
        // sP next write is after barriers (1)+(2) -> out-store read is safe
    }
}

extern "C" void kernel_launch(void* const* d_in, const int* in_sizes, int n_in,
                              void* d_out, int out_size, void* d_ws, size_t ws_size,
                              hipStream_t stream) {
    const float* pos     = (const float*)d_in[0];
    const float* nodef   = (const float*)d_in[1];
    const float* origin  = (const float*)d_in[2];
    const float* lattice = (const float*)d_in[3];
    const float* scale   = (const float*)d_in[4];
    const float* W1      = (const float*)d_in[5];
    const float* b1      = (const float*)d_in[6];
    const float* W2      = (const float*)d_in[7];
    const float* b2      = (const float*)d_in[8];
    const int*   bn      = (const int*)d_in[9];
    float* outP = (float*)d_out;
    float* cP   = outP + OUTOFF;

    hipLaunchKernelGGL(density_mfma_kernel, dim3(4 * CPB), dim3(256), 0, stream,
                       pos, nodef, origin, lattice, scale, W1, b1, W2, b2, bn,
                       outP, cP);
}